// Round 1
// baseline (164.339 us; speedup 1.0000x reference)
//
#include <hip/hip_runtime.h>
#include <math.h>

#define DEV static __device__ __forceinline__

constexpr int BB = 64;
constexpr int SS = 12;
constexpr int NN = 207;
constexpr int NCIRC = BB * NN;          // 13248 circuits, 4 waves/block -> 3312 blocks

// Lane layout: amplitude index i = (lane<<2) | k, k=0..3.
// Amplitude bit p: p=0,1 -> in-lane (k bits); p>=2 -> lane bit (p-2).
// Qubit w corresponds to amplitude bit (7-w).

struct St { float re[4]; float im[4]; };

DEV float sx(float v, int m) { return __shfl_xor(v, m, 64); }

template<int P>
DEV void ry_gate(St& st, float c, float s) {
    if constexpr (P == 0) {
        float r0=st.re[0], r1=st.re[1], i0=st.im[0], i1=st.im[1];
        st.re[0] = fmaf(c, r0, -s*r1); st.re[1] = fmaf(s, r0, c*r1);
        st.im[0] = fmaf(c, i0, -s*i1); st.im[1] = fmaf(s, i0, c*i1);
        float r2=st.re[2], r3=st.re[3], i2=st.im[2], i3=st.im[3];
        st.re[2] = fmaf(c, r2, -s*r3); st.re[3] = fmaf(s, r2, c*r3);
        st.im[2] = fmaf(c, i2, -s*i3); st.im[3] = fmaf(s, i2, c*i3);
    } else if constexpr (P == 1) {
        float r0=st.re[0], r2=st.re[2], i0=st.im[0], i2=st.im[2];
        st.re[0] = fmaf(c, r0, -s*r2); st.re[2] = fmaf(s, r0, c*r2);
        st.im[0] = fmaf(c, i0, -s*i2); st.im[2] = fmaf(s, i0, c*i2);
        float r1=st.re[1], r3=st.re[3], i1=st.im[1], i3=st.im[3];
        st.re[1] = fmaf(c, r1, -s*r3); st.re[3] = fmaf(s, r1, c*r3);
        st.im[1] = fmaf(c, i1, -s*i3); st.im[3] = fmaf(s, i1, c*i3);
    } else {
        constexpr int lm = 1 << (P - 2);
        const float sg = ((threadIdx.x >> (P - 2)) & 1) ? s : -s;
#pragma unroll
        for (int k = 0; k < 4; k++) {
            float pr = sx(st.re[k], lm), pi = sx(st.im[k], lm);
            st.re[k] = fmaf(c, st.re[k], sg * pr);
            st.im[k] = fmaf(c, st.im[k], sg * pi);
        }
    }
}

template<int PC, int PT>
DEV void cnot_gate(St& st) {
    if constexpr (PT >= 2) {
        constexpr int lm = 1 << (PT - 2);
        if constexpr (PC >= 2) {
            const bool b = (threadIdx.x >> (PC - 2)) & 1;
#pragma unroll
            for (int k = 0; k < 4; k++) {
                float pr = sx(st.re[k], lm), pi = sx(st.im[k], lm);
                st.re[k] = b ? pr : st.re[k];
                st.im[k] = b ? pi : st.im[k];
            }
        } else {
#pragma unroll
            for (int k = 0; k < 4; k++) {
                if ((k >> PC) & 1) {
                    st.re[k] = sx(st.re[k], lm);
                    st.im[k] = sx(st.im[k], lm);
                }
            }
        }
    } else {
        if constexpr (PC >= 2) {
            const bool b = (threadIdx.x >> (PC - 2)) & 1;
            float tr[4] = {st.re[0], st.re[1], st.re[2], st.re[3]};
            float ti[4] = {st.im[0], st.im[1], st.im[2], st.im[3]};
#pragma unroll
            for (int k = 0; k < 4; k++) {
                st.re[k] = b ? tr[k ^ (1 << PT)] : st.re[k];
                st.im[k] = b ? ti[k ^ (1 << PT)] : st.im[k];
            }
        } else {
            float tr[4] = {st.re[0], st.re[1], st.re[2], st.re[3]};
            float ti[4] = {st.im[0], st.im[1], st.im[2], st.im[3]};
#pragma unroll
            for (int k = 0; k < 4; k++) {
                if ((k >> PC) & 1) {
                    st.re[k] = tr[k ^ (1 << PT)];
                    st.im[k] = ti[k ^ (1 << PT)];
                }
            }
        }
    }
}

// ---- pre-kernel: cos/sin table for the 64 q_params half-angles ----
__global__ void trig_kernel(const float* __restrict__ qp, float* __restrict__ tab) {
    int i = threadIdx.x;
    if (i < 64) {
        float s, c;
        sincosf(0.5f * qp[i], &s, &c);
        tab[2 * i]     = c;
        tab[2 * i + 1] = s;
    }
}

// conv pair: RY(p0) q1; RY(p1) q2; CNOT(q1->q2); RY(p2) q1; RY(p3) q2; CNOT(q2->q1)
#define CONV_PAIR(Q1, Q2, J)                                            \
    ry_gate<7 - (Q1)>(st, tab[2*(J)],     tab[2*(J) + 1]);              \
    ry_gate<7 - (Q2)>(st, tab[2*(J) + 2], tab[2*(J) + 3]);              \
    cnot_gate<7 - (Q1), 7 - (Q2)>(st);                                  \
    ry_gate<7 - (Q1)>(st, tab[2*(J) + 4], tab[2*(J) + 5]);              \
    ry_gate<7 - (Q2)>(st, tab[2*(J) + 6], tab[2*(J) + 7]);              \
    cnot_gate<7 - (Q2), 7 - (Q1)>(st);

__global__ __launch_bounds__(256) void qcnn_kernel(
    const float* __restrict__ x, const float* __restrict__ adj,
    const float* __restrict__ w_proj, const float* __restrict__ b_proj,
    const float* __restrict__ tab,
    const float* __restrict__ w1, const float* __restrict__ b1,
    const float* __restrict__ w2, const float* __restrict__ b2,
    const float* __restrict__ w3, const float* __restrict__ b3,
    float* __restrict__ out)
{
    const int lane = threadIdx.x & 63;
    const int wv   = threadIdx.x >> 6;
    const int g    = blockIdx.x * 4 + wv;        // grid is exact: 3312*4 == 13248
    const int b    = g / NN;
    const int node = g - b * NN;

    // ---- angles = x-slice @ w_proj.T + b_proj, clipped to [-pi, pi] ----
    float ang[8];
#pragma unroll
    for (int k = 0; k < 8; k++) ang[k] = b_proj[k];
    const float* xp = x + ((size_t)b * SS * NN + node) * 2;
#pragma unroll
    for (int s = 0; s < SS; s++) {
        float x0 = xp[(size_t)s * (NN * 2)];
        float x1 = xp[(size_t)s * (NN * 2) + 1];
#pragma unroll
        for (int k = 0; k < 8; k++) {
            ang[k] = fmaf(x0, w_proj[k * 24 + 2 * s],     ang[k]);
            ang[k] = fmaf(x1, w_proj[k * 24 + 2 * s + 1], ang[k]);
        }
    }
    const float PI_F = 3.14159265358979323846f;
#pragma unroll
    for (int k = 0; k < 8; k++) ang[k] = fminf(fmaxf(ang[k], -PI_F), PI_F);

    // ---- build product state after RY layer + RZ phases analytically ----
    // qubit i -> amplitude bit (7-i); bits 2..7 are lane bits 0..5
    float cc[8], ss[8];
#pragma unroll
    for (int i = 0; i < 8; i++) sincosf(0.5f * ang[i], &ss[i], &cc[i]);

    float A = 1.0f;
#pragma unroll
    for (int i = 0; i < 6; i++) {            // qubits 0..5 -> lane bits 5-i
        int bit = (threadIdx.x >> (5 - i)) & 1;
        A *= bit ? ss[i] : cc[i];
    }
    // RZ on qubits 0..3 (lane bits 5..2): phase = sum(+-ang[4+i]/2)
    float phi = 0.0f;
#pragma unroll
    for (int i = 0; i < 4; i++) {
        int bit = (threadIdx.x >> (5 - i)) & 1;
        phi += bit ? 0.5f * ang[4 + i] : -0.5f * ang[4 + i];
    }
    float cp, sp;
    sincosf(phi, &sp, &cp);

    St st;
#pragma unroll
    for (int k = 0; k < 4; k++) {            // qubit6 -> k bit1, qubit7 -> k bit0
        float Ak = A * ((k & 2) ? ss[6] : cc[6]) * ((k & 1) ? ss[7] : cc[7]);
        st.re[k] = Ak * cp;
        st.im[k] = Ak * sp;
    }

    // ---- adjacency-controlled CNOT chain == single XOR-mask permutation ----
    const int c = node & 7;
    int M = 0;
#pragma unroll
    for (int t = 0; t < 8; t++) {
        float av = adj[c * NN + t];
        if (t != c && av > 0.0f) M |= 1 << (7 - t);
    }
    if (M) {
        const int Mlane = M >> 2;
        const int Mlo   = M & 3;
        float pr[4], pim[4];
        if (Mlo == 0) {
            pr[0]=sx(st.re[0],Mlane); pr[1]=sx(st.re[1],Mlane); pr[2]=sx(st.re[2],Mlane); pr[3]=sx(st.re[3],Mlane);
            pim[0]=sx(st.im[0],Mlane); pim[1]=sx(st.im[1],Mlane); pim[2]=sx(st.im[2],Mlane); pim[3]=sx(st.im[3],Mlane);
        } else if (Mlo == 1) {
            pr[0]=sx(st.re[1],Mlane); pr[1]=sx(st.re[0],Mlane); pr[2]=sx(st.re[3],Mlane); pr[3]=sx(st.re[2],Mlane);
            pim[0]=sx(st.im[1],Mlane); pim[1]=sx(st.im[0],Mlane); pim[2]=sx(st.im[3],Mlane); pim[3]=sx(st.im[2],Mlane);
        } else if (Mlo == 2) {
            pr[0]=sx(st.re[2],Mlane); pr[1]=sx(st.re[3],Mlane); pr[2]=sx(st.re[0],Mlane); pr[3]=sx(st.re[1],Mlane);
            pim[0]=sx(st.im[2],Mlane); pim[1]=sx(st.im[3],Mlane); pim[2]=sx(st.im[0],Mlane); pim[3]=sx(st.im[1],Mlane);
        } else {
            pr[0]=sx(st.re[3],Mlane); pr[1]=sx(st.re[2],Mlane); pr[2]=sx(st.re[1],Mlane); pr[3]=sx(st.re[0],Mlane);
            pim[0]=sx(st.im[3],Mlane); pim[1]=sx(st.im[2],Mlane); pim[2]=sx(st.im[1],Mlane); pim[3]=sx(st.im[0],Mlane);
        }
        const int pc = 7 - c;                 // control amplitude bit
        if (pc >= 2) {
            const bool bb = (threadIdx.x >> (pc - 2)) & 1;
#pragma unroll
            for (int k = 0; k < 4; k++) {
                st.re[k] = bb ? pr[k]  : st.re[k];
                st.im[k] = bb ? pim[k] : st.im[k];
            }
        } else {
#pragma unroll
            for (int k = 0; k < 4; k++) {
                const bool bb = (k >> pc) & 1;
                st.re[k] = bb ? pr[k]  : st.re[k];
                st.im[k] = bb ? pim[k] : st.im[k];
            }
        }
    }

    // ---- conv layers (angles from precomputed table; same for all circuits) ----
    // layer 1
    CONV_PAIR(0, 1, 0);  CONV_PAIR(2, 3, 4);  CONV_PAIR(4, 5, 8);  CONV_PAIR(6, 7, 12);
    CONV_PAIR(1, 2, 16); CONV_PAIR(3, 4, 20); CONV_PAIR(5, 6, 24);
    // layer 2
    CONV_PAIR(0, 1, 28); CONV_PAIR(2, 3, 32); CONV_PAIR(4, 5, 36); CONV_PAIR(6, 7, 40);
    CONV_PAIR(1, 2, 44); CONV_PAIR(3, 4, 48); CONV_PAIR(5, 6, 52);

    // ---- pool: RY(qp[56+q]) on q = 0,2,4,6 -> bits 7,5,3,1 ----
    ry_gate<7>(st, tab[2 * 56], tab[2 * 56 + 1]);
    ry_gate<5>(st, tab[2 * 58], tab[2 * 58 + 1]);
    ry_gate<3>(st, tab[2 * 60], tab[2 * 60 + 1]);
    ry_gate<1>(st, tab[2 * 62], tab[2 * 62 + 1]);

    // ---- z[w] = sum probs * (1 - 2*bit_w) ----
    float p0 = fmaf(st.re[0], st.re[0], st.im[0] * st.im[0]);
    float p1 = fmaf(st.re[1], st.re[1], st.im[1] * st.im[1]);
    float p2 = fmaf(st.re[2], st.re[2], st.im[2] * st.im[2]);
    float p3 = fmaf(st.re[3], st.re[3], st.im[3] * st.im[3]);
    float psum = (p0 + p1) + (p2 + p3);
    float zv[8];
    zv[7] = (p0 - p1) + (p2 - p3);           // bit0 (qubit 7)
    zv[6] = (p0 + p1) - (p2 + p3);           // bit1 (qubit 6)
#pragma unroll
    for (int q = 0; q < 6; q++)              // lane bit q -> qubit 5-q
        zv[5 - q] = ((threadIdx.x >> q) & 1) ? -psum : psum;

    // butterfly reduce -> every lane holds the full z vector
#pragma unroll
    for (int m = 1; m < 64; m <<= 1) {
#pragma unroll
        for (int w = 0; w < 8; w++) zv[w] += sx(zv[w], m);
    }

    // ---- MLP head: 8 -> 64 (relu) -> 32 (relu) -> 1 ----
    float h1 = b1[lane];
#pragma unroll
    for (int k = 0; k < 8; k++) h1 = fmaf(zv[k], w1[lane * 8 + k], h1);
    h1 = fmaxf(h1, 0.0f);

    __shared__ float h1s[4][64];
    h1s[wv][lane] = h1;
    __syncthreads();

    const int m = lane & 31;
    float h2 = b2[m];
#pragma unroll
    for (int j = 0; j < 64; j++) h2 = fmaf(h1s[wv][j], w2[m * 64 + j], h2);
    h2 = fmaxf(h2, 0.0f);

    float o = h2 * w3[m];
#pragma unroll
    for (int mm = 1; mm < 32; mm <<= 1) o += sx(o, mm);

    if (lane == 0) out[g] = o + b3[0];
}

extern "C" void kernel_launch(void* const* d_in, const int* in_sizes, int n_in,
                              void* d_out, int out_size, void* d_ws, size_t ws_size,
                              hipStream_t stream) {
    const float* x      = (const float*)d_in[0];
    const float* adj    = (const float*)d_in[1];
    const float* w_proj = (const float*)d_in[2];
    const float* b_proj = (const float*)d_in[3];
    const float* qp     = (const float*)d_in[4];
    const float* w1     = (const float*)d_in[5];
    const float* b1     = (const float*)d_in[6];
    const float* w2     = (const float*)d_in[7];
    const float* b2     = (const float*)d_in[8];
    const float* w3     = (const float*)d_in[9];
    const float* b3     = (const float*)d_in[10];
    float* out = (float*)d_out;
    float* tab = (float*)d_ws;                 // 128 floats

    hipLaunchKernelGGL(trig_kernel, dim3(1), dim3(64), 0, stream, qp, tab);
    hipLaunchKernelGGL(qcnn_kernel, dim3(NCIRC / 4), dim3(256), 0, stream,
                       x, adj, w_proj, b_proj, tab, w1, b1, w2, b2, w3, b3, out);
}

// Round 2
// 151.445 us; speedup vs baseline: 1.0851x; 1.0851x over previous
//
#include <hip/hip_runtime.h>
#include <math.h>

#define DEV static __device__ __forceinline__

constexpr int BB = 64;
constexpr int SS = 12;
constexpr int NN = 207;
constexpr int NCIRC = BB * NN;          // 13248 circuits, 4 waves/block -> 3312 blocks

// Lane layout: amplitude index i = (lane<<2) | k, k=0..3.
// Amp bit 0,1 = "K slots" (in-lane); amp bit b>=2 = lane bit b-2 ("L slots").
// Initially qubit q sits at amp bit (7-q): q6->K1, q7->K0, q0..q5 -> L5..L0.
// Conv pairs are computed with BOTH qubits in K slots (pure register math);
// swap_kl<KB>(lambda) exchanges K-bit KB with lane bit lambda (8 bpermutes).

struct St { float re[4]; float im[4]; };

DEV float bperm(int addr, float v) {
    return __int_as_float(__builtin_amdgcn_ds_bpermute(addr, __float_as_int(v)));
}

// RY on in-lane amplitude bit KB: pure FMAs.
template<int KB>
DEV void ry_k(St& st, float c, float s) {
    if constexpr (KB == 0) {
        float r0=st.re[0], r1=st.re[1], i0=st.im[0], i1=st.im[1];
        st.re[0] = fmaf(c, r0, -s*r1); st.re[1] = fmaf(s, r0, c*r1);
        st.im[0] = fmaf(c, i0, -s*i1); st.im[1] = fmaf(s, i0, c*i1);
        float r2=st.re[2], r3=st.re[3], i2=st.im[2], i3=st.im[3];
        st.re[2] = fmaf(c, r2, -s*r3); st.re[3] = fmaf(s, r2, c*r3);
        st.im[2] = fmaf(c, i2, -s*i3); st.im[3] = fmaf(s, i2, c*i3);
    } else {
        float r0=st.re[0], r2=st.re[2], i0=st.im[0], i2=st.im[2];
        st.re[0] = fmaf(c, r0, -s*r2); st.re[2] = fmaf(s, r0, c*r2);
        st.im[0] = fmaf(c, i0, -s*i2); st.im[2] = fmaf(s, i0, c*i2);
        float r1=st.re[1], r3=st.re[3], i1=st.im[1], i3=st.im[3];
        st.re[1] = fmaf(c, r1, -s*r3); st.re[3] = fmaf(s, r1, c*r3);
        st.im[1] = fmaf(c, i1, -s*i3); st.im[3] = fmaf(s, i1, c*i3);
    }
}

// CNOT with both control (bit CB) and target (bit TB) in-lane: register rename.
template<int CB, int TB>
DEV void cnot_kk(St& st) {
    if constexpr (CB == 1 && TB == 0) {
        float t = st.re[2]; st.re[2] = st.re[3]; st.re[3] = t;
        t = st.im[2]; st.im[2] = st.im[3]; st.im[3] = t;
    } else {  // CB==0, TB==1
        float t = st.re[1]; st.re[1] = st.re[3]; st.re[3] = t;
        t = st.im[1]; st.im[1] = st.im[3]; st.im[3] = t;
    }
}

// Swap in-lane amp bit KB with lane bit lambda. addr = precomputed bpermute
// address for partner lane (lane ^ (1<<lambda)) << 2; lb = this lane's bit.
template<int KB>
DEV void swap_kl(St& st, int addr, bool lb) {
    constexpr int m = 1 << KB;
    float tr[4], ti[4];
#pragma unroll
    for (int k = 0; k < 4; k++) {
        tr[k] = bperm(addr, st.re[k ^ m]);
        ti[k] = bperm(addr, st.im[k ^ m]);
    }
#pragma unroll
    for (int k = 0; k < 4; k++) {
        const bool keep = ((((k >> KB) & 1) != 0) == lb);   // fixed point
        st.re[k] = keep ? st.re[k] : tr[k];
        st.im[k] = keep ? st.im[k] : ti[k];
    }
}

// RY on a lane-resident qubit (used only for the 3 pool gates).
DEV void ry_lane(St& st, int addr, bool lb, float c, float s) {
    const float sg = lb ? s : -s;
#pragma unroll
    for (int k = 0; k < 4; k++) {
        float pr = bperm(addr, st.re[k]);
        float pi = bperm(addr, st.im[k]);
        st.re[k] = fmaf(c, st.re[k], sg * pr);
        st.im[k] = fmaf(c, st.im[k], sg * pi);
    }
}

// Conv pair with qubit q1 at K-bit KA, qubit q2 at K-bit KB2. t8 = &tab[2*J].
template<int KA, int KB2>
DEV void conv_kk(St& st, const float* __restrict__ t8) {
    ry_k<KA>(st, t8[0], t8[1]);
    ry_k<KB2>(st, t8[2], t8[3]);
    cnot_kk<KA, KB2>(st);
    ry_k<KA>(st, t8[4], t8[5]);
    ry_k<KB2>(st, t8[6], t8[7]);
    cnot_kk<KB2, KA>(st);
}

// ---- pre-kernel: cos/sin table for the 64 q_params half-angles ----
__global__ void trig_kernel(const float* __restrict__ qp, float* __restrict__ tab) {
    int i = threadIdx.x;
    if (i < 64) {
        float s, c;
        sincosf(0.5f * qp[i], &s, &c);
        tab[2 * i]     = c;
        tab[2 * i + 1] = s;
    }
}

__global__ __launch_bounds__(256) void qcnn_kernel(
    const float* __restrict__ x, const float* __restrict__ adj,
    const float* __restrict__ w_proj, const float* __restrict__ b_proj,
    const float* __restrict__ tab,
    const float* __restrict__ w1, const float* __restrict__ b1,
    const float* __restrict__ w2, const float* __restrict__ b2,
    const float* __restrict__ w3, const float* __restrict__ b3,
    float* __restrict__ out)
{
    const int lane = threadIdx.x & 63;
    const int wv   = threadIdx.x >> 6;
    const int g    = blockIdx.x * 4 + wv;        // grid exact: 3312*4 == 13248
    const int b    = g / NN;
    const int node = g - b * NN;

    // Precomputed bpermute addresses for XOR masks 1,2,4,8,16,32 and lane bits.
    int baddr[6];
    bool lb[6];
#pragma unroll
    for (int j = 0; j < 6; j++) {
        baddr[j] = (lane ^ (1 << j)) << 2;
        lb[j]    = (lane >> j) & 1;
    }

    // ---- angles = x-slice @ w_proj.T + b_proj, clipped to [-pi, pi] ----
    float ang[8];
#pragma unroll
    for (int k = 0; k < 8; k++) ang[k] = b_proj[k];
    const float* xp = x + ((size_t)b * SS * NN + node) * 2;
#pragma unroll
    for (int s = 0; s < SS; s++) {
        float x0 = xp[(size_t)s * (NN * 2)];
        float x1 = xp[(size_t)s * (NN * 2) + 1];
#pragma unroll
        for (int k = 0; k < 8; k++) {
            ang[k] = fmaf(x0, w_proj[k * 24 + 2 * s],     ang[k]);
            ang[k] = fmaf(x1, w_proj[k * 24 + 2 * s + 1], ang[k]);
        }
    }
    const float PI_F = 3.14159265358979323846f;
#pragma unroll
    for (int k = 0; k < 8; k++) ang[k] = fminf(fmaxf(ang[k], -PI_F), PI_F);

    // ---- product state after RY layer + RZ phases, built analytically ----
    float cc[8], ss[8];
#pragma unroll
    for (int i = 0; i < 8; i++) sincosf(0.5f * ang[i], &ss[i], &cc[i]);

    float A = 1.0f;
#pragma unroll
    for (int i = 0; i < 6; i++) {            // qubits 0..5 -> lane bits 5-i
        A *= ((threadIdx.x >> (5 - i)) & 1) ? ss[i] : cc[i];
    }
    float phi = 0.0f;
#pragma unroll
    for (int i = 0; i < 4; i++) {            // RZ on qubits 0..3 (lane bits 5..2)
        phi += ((threadIdx.x >> (5 - i)) & 1) ? 0.5f * ang[4 + i] : -0.5f * ang[4 + i];
    }
    float cp, sp;
    sincosf(phi, &sp, &cp);

    St st;
#pragma unroll
    for (int k = 0; k < 4; k++) {            // qubit6 -> k bit1, qubit7 -> k bit0
        float Ak = A * ((k & 2) ? ss[6] : cc[6]) * ((k & 1) ? ss[7] : cc[7]);
        st.re[k] = Ak * cp;
        st.im[k] = Ak * sp;
    }

    // ---- adjacency-controlled CNOT chain == single XOR-mask permutation ----
    const int c = node & 7;
    int M = 0;
#pragma unroll
    for (int t = 0; t < 8; t++) {
        float av = adj[c * NN + t];
        if (t != c && av > 0.0f) M |= 1 << (7 - t);
    }
    if (M) {
        const int Mlane = M >> 2;
        const int Mlo   = M & 3;
        const int addrM = (lane ^ Mlane) << 2;
        float pr[4], pim[4];
#pragma unroll
        for (int k = 0; k < 4; k++) {
            pr[k]  = bperm(addrM, st.re[k ^ Mlo]);
            pim[k] = bperm(addrM, st.im[k ^ Mlo]);
        }
        const int pc = 7 - c;                 // control amplitude bit
        if (pc >= 2) {
            const bool bb = (threadIdx.x >> (pc - 2)) & 1;
#pragma unroll
            for (int k = 0; k < 4; k++) {
                st.re[k] = bb ? pr[k]  : st.re[k];
                st.im[k] = bb ? pim[k] : st.im[k];
            }
        } else {
#pragma unroll
            for (int k = 0; k < 4; k++) {
                const bool bb = (k >> pc) & 1;
                st.re[k] = bb ? pr[k]  : st.re[k];
                st.im[k] = bb ? pim[k] : st.im[k];
            }
        }
    }

    // ---- conv layers with dynamic relayout ----
    // Slot map tracked in comments: K1,K0 | L5,L4,L3,L2,L1,L0 (values = qubit)
    //                      init:  6,7 | 0,1,2,3,4,5
    conv_kk<1,0>(st, tab + 2*12);                        // (6,7)
    swap_kl<1>(st, baddr[1], lb[1]);                     // 4,7 | 0,1,2,3,6,5
    swap_kl<0>(st, baddr[0], lb[0]);                     // 4,5 | 0,1,2,3,6,7
    conv_kk<1,0>(st, tab + 2*8);                         // (4,5)
    swap_kl<1>(st, baddr[1], lb[1]);                     // 6,5 | 0,1,2,3,4,7
    conv_kk<0,1>(st, tab + 2*24);                        // (5,6): q5=K0,q6=K1
    swap_kl<1>(st, baddr[3], lb[3]);                     // 2,5 | 0,1,6,3,4,7
    swap_kl<0>(st, baddr[2], lb[2]);                     // 2,3 | 0,1,6,5,4,7
    conv_kk<1,0>(st, tab + 2*4);                         // (2,3)
    swap_kl<1>(st, baddr[1], lb[1]);                     // 4,3 | 0,1,6,5,2,7
    conv_kk<0,1>(st, tab + 2*20);                        // (3,4): q3=K0,q4=K1
    swap_kl<1>(st, baddr[5], lb[5]);                     // 0,3 | 4,1,6,5,2,7
    swap_kl<0>(st, baddr[4], lb[4]);                     // 0,1 | 4,3,6,5,2,7
    conv_kk<1,0>(st, tab + 2*0);                         // (0,1)
    swap_kl<1>(st, baddr[1], lb[1]);                     // 2,1 | 4,3,6,5,0,7
    conv_kk<0,1>(st, tab + 2*16);                        // (1,2): q1=K0,q2=K1
    // ---- layer 2 ----
    swap_kl<0>(st, baddr[4], lb[4]);                     // 2,3 | 4,1,6,5,0,7
    conv_kk<1,0>(st, tab + 2*32);                        // (2,3)
    swap_kl<1>(st, baddr[1], lb[1]);                     // 0,3 | 4,1,6,5,2,7
    swap_kl<0>(st, baddr[4], lb[4]);                     // 0,1 | 4,3,6,5,2,7
    conv_kk<1,0>(st, tab + 2*28);                        // (0,1)
    swap_kl<1>(st, baddr[1], lb[1]);                     // 2,1 | 4,3,6,5,0,7
    conv_kk<0,1>(st, tab + 2*44);                        // (1,2)
    swap_kl<1>(st, baddr[5], lb[5]);                     // 4,1 | 2,3,6,5,0,7
    swap_kl<0>(st, baddr[2], lb[2]);                     // 4,5 | 2,3,6,1,0,7
    conv_kk<1,0>(st, tab + 2*36);                        // (4,5)
    swap_kl<0>(st, baddr[4], lb[4]);                     // 4,3 | 2,5,6,1,0,7
    conv_kk<0,1>(st, tab + 2*48);                        // (3,4)
    swap_kl<1>(st, baddr[3], lb[3]);                     // 6,3 | 2,5,4,1,0,7
    swap_kl<0>(st, baddr[0], lb[0]);                     // 6,7 | 2,5,4,1,0,3
    conv_kk<1,0>(st, tab + 2*40);                        // (6,7)
    swap_kl<0>(st, baddr[4], lb[4]);                     // 6,5 | 2,7,4,1,0,3
    conv_kk<0,1>(st, tab + 2*52);                        // (5,6)
    // final layout: K1=q6, K0=q5 | L5=q2, L4=q7, L3=q4, L2=q1, L1=q0, L0=q3

    // ---- pool: RY on q0(L1), q2(L5), q4(L3), q6(K1) ----
    ry_lane(st, baddr[1], lb[1], tab[112], tab[113]);    // q0
    ry_lane(st, baddr[5], lb[5], tab[116], tab[117]);    // q2
    ry_lane(st, baddr[3], lb[3], tab[120], tab[121]);    // q4
    ry_k<1>(st, tab[124], tab[125]);                     // q6

    // ---- z[q] from probabilities, per final layout ----
    float p0 = fmaf(st.re[0], st.re[0], st.im[0] * st.im[0]);
    float p1 = fmaf(st.re[1], st.re[1], st.im[1] * st.im[1]);
    float p2 = fmaf(st.re[2], st.re[2], st.im[2] * st.im[2]);
    float p3 = fmaf(st.re[3], st.re[3], st.im[3] * st.im[3]);
    float psum = (p0 + p1) + (p2 + p3);
    float zv[8];
    zv[6] = (p0 + p1) - (p2 + p3);           // K1 = q6
    zv[5] = (p0 - p1) + (p2 - p3);           // K0 = q5
    zv[2] = lb[5] ? -psum : psum;            // L5 = q2
    zv[7] = lb[4] ? -psum : psum;            // L4 = q7
    zv[4] = lb[3] ? -psum : psum;            // L3 = q4
    zv[1] = lb[2] ? -psum : psum;            // L2 = q1
    zv[0] = lb[1] ? -psum : psum;            // L1 = q0
    zv[3] = lb[0] ? -psum : psum;            // L0 = q3

    // butterfly reduce -> every lane holds the full z vector
#pragma unroll
    for (int j = 0; j < 6; j++) {
#pragma unroll
        for (int w = 0; w < 8; w++) zv[w] += bperm(baddr[j], zv[w]);
    }

    // ---- MLP head: 8 -> 64 (relu) -> 32 (relu) -> 1 ----
    float h1 = b1[lane];
#pragma unroll
    for (int k = 0; k < 8; k++) h1 = fmaf(zv[k], w1[lane * 8 + k], h1);
    h1 = fmaxf(h1, 0.0f);

    __shared__ float h1s[4][64];
    h1s[wv][lane] = h1;
    __syncthreads();

    const int m = lane & 31;
    float h2 = b2[m];
#pragma unroll
    for (int j = 0; j < 64; j++) h2 = fmaf(h1s[wv][j], w2[m * 64 + j], h2);
    h2 = fmaxf(h2, 0.0f);

    float o = h2 * w3[m];
#pragma unroll
    for (int j = 0; j < 5; j++) o += bperm(baddr[j], o);

    if (lane == 0) out[g] = o + b3[0];
}

extern "C" void kernel_launch(void* const* d_in, const int* in_sizes, int n_in,
                              void* d_out, int out_size, void* d_ws, size_t ws_size,
                              hipStream_t stream) {
    const float* x      = (const float*)d_in[0];
    const float* adj    = (const float*)d_in[1];
    const float* w_proj = (const float*)d_in[2];
    const float* b_proj = (const float*)d_in[3];
    const float* qp     = (const float*)d_in[4];
    const float* w1     = (const float*)d_in[5];
    const float* b1     = (const float*)d_in[6];
    const float* w2     = (const float*)d_in[7];
    const float* b2     = (const float*)d_in[8];
    const float* w3     = (const float*)d_in[9];
    const float* b3     = (const float*)d_in[10];
    float* out = (float*)d_out;
    float* tab = (float*)d_ws;                 // 128 floats

    hipLaunchKernelGGL(trig_kernel, dim3(1), dim3(64), 0, stream, qp, tab);
    hipLaunchKernelGGL(qcnn_kernel, dim3(NCIRC / 4), dim3(256), 0, stream,
                       x, adj, w_proj, b_proj, tab, w1, b1, w2, b2, w3, b3, out);
}